// Round 1
// 75.746 us; speedup vs baseline: 1.0137x; 1.0137x over previous
//
#include <hip/hip_runtime.h>
#include <math.h>

#define N_KCS 5000
#define TT    100
#define BB    512

__device__ __forceinline__ float sigmoidf(float x) {
    return 1.0f / (1.0f + expf(-x));
}

// Single fused kernel: one workgroup per batch row, no workspace, no sigmoid
// table round-trip. All sigmoids computed on the fly from logits with the
// SAME inlined sigmoidf -> bit-identical to the previous two-kernel version.
//
// Key structural facts (unchanged from verified kernel):
//  - chains over equal prev_kc are resolved by head lanes walking nxt_s[]
//  - cs at step t = pred at last t' <= t with pk[t'] == ck[t], else pristine init
//  - final state row = init row with <=99 chain-tail overrides
__global__ __launch_bounds__(256) void bkt_fused_kernel(
    const int*   __restrict__ prev_kc,
    const int*   __restrict__ curr_kc,
    const int*   __restrict__ prev_corr,
    const float* __restrict__ logits,     // (N_KCS, 5)
    float*       __restrict__ probs_out,  // (B, T)
    float*       __restrict__ state_out)  // (B, N_KCS)
{
    __shared__ int   pk_s[TT], ck_s[TT], nxt_s[TT];
    __shared__ float po0_s[TT], po1_s[TT], pp0_s[TT], pp1_s[TT];
    __shared__ float cp2_s[TT], cp3_s[TT], pred_s[TT];

    const int b    = blockIdx.x;
    const int tid  = threadIdx.x;
    const int base = b * TT;

    if (tid < TT) {
        pk_s[tid] = prev_kc[base + tid];
        ck_s[tid] = curr_kc[base + tid];
    }
    __syncthreads();

    const int  t   = tid;
    const bool act = (t >= 1 && t < TT);
    int   lst     = -1;    // last t' <= t with pk[t'] == ck[t]
    bool  head    = true;  // no t' <  t with pk[t'] == pk[t]
    float init_pk = 0.0f;  // pristine init for this thread's pk chain head

    if (act) {
        const int mypk = pk_s[t];
        const int myck = ck_s[t];
        const int c    = prev_corr[base + t];

        // state-independent per-step constants (logits gathers are L2/L3 hits)
        float pp2 = sigmoidf(logits[mypk * 5 + 2]);
        float pp3 = sigmoidf(logits[mypk * 5 + 3]);
        pp0_s[t]  = sigmoidf(logits[mypk * 5 + 0]);
        pp1_s[t]  = sigmoidf(logits[mypk * 5 + 1]);
        cp2_s[t]  = sigmoidf(logits[myck * 5 + 2]);
        cp3_s[t]  = sigmoidf(logits[myck * 5 + 3]);
        // pch^c * (1-pch)^(1-c) with c in {0,1} == select (bit-exact)
        po0_s[t]  = c ? pp2 : (1.0f - pp2);
        po1_s[t]  = c ? pp3 : (1.0f - pp3);
        init_pk   = sigmoidf(logits[mypk * 5 + 4]);

        // parallel linkage: scan all step indices (LDS broadcast reads)
        int nxt = -1;
        for (int tp = 1; tp < TT; ++tp) {
            int p = pk_s[tp];
            if (p == mypk) {
                if (tp < t)                    head = false;
                else if (tp > t && nxt == -1)  nxt  = tp;
            }
            if (p == myck && tp <= t) lst = tp;   // increasing tp -> keeps max
        }
        nxt_s[t] = nxt;
    }

    // t = 0 prob: state untouched, cs0 = pristine init of ck0
    if (t == 0) {
        int   ck0 = ck_s[0];
        float cs0 = sigmoidf(logits[ck0 * 5 + 4]);
        probs_out[base] = sigmoidf(logits[ck0 * 5 + 2]) * (1.0f - cs0)
                        + sigmoidf(logits[ck0 * 5 + 3]) * cs0;
    }
    __syncthreads();

    // chain walk: head lanes evaluate their kc-chain sequentially
    // (arithmetic identical to the reference scan step)
    if (act && head) {
        float s = init_pk;
        int   u = t;
        while (u != -1) {
            float num        = po1_s[u] * s;
            float filt       = num / (po0_s[u] * (1.0f - s) + num);
            float predictive = pp0_s[u] * (1.0f - filt) + (1.0f - pp1_s[u]) * filt;
            pred_s[u] = predictive;
            s = predictive;
            u = nxt_s[u];
        }
    }
    __syncthreads();

    // probs: cs = pred at last write <= t, else pristine init
    if (act) {
        float cs = (lst == -1) ? sigmoidf(logits[ck_s[t] * 5 + 4]) : pred_s[lst];
        probs_out[base + t] = cp2_s[t] * (1.0f - cs) + cp3_s[t] * cs;
    }

    // full-row init write: float4-coalesced stores; logits col-4 gather is
    // a 20B-stride read of the 100 KB L3-resident table
    float* out_row = state_out + (size_t)b * N_KCS;
    for (int k4 = tid * 4; k4 < N_KCS; k4 += 256 * 4) {   // N_KCS % 4 == 0
        float4 v;
        v.x = sigmoidf(logits[(k4 + 0) * 5 + 4]);
        v.y = sigmoidf(logits[(k4 + 1) * 5 + 4]);
        v.z = sigmoidf(logits[(k4 + 2) * 5 + 4]);
        v.w = sigmoidf(logits[(k4 + 3) * 5 + 4]);
        *(float4*)&out_row[k4] = v;
    }
    __syncthreads();   // all init stores of this block land before overrides

    // chain-tail overrides into the output row
    if (act && nxt_s[t] == -1) {
        out_row[pk_s[t]] = pred_s[t];
    }
}

extern "C" void kernel_launch(void* const* d_in, const int* in_sizes, int n_in,
                              void* d_out, int out_size, void* d_ws, size_t ws_size,
                              hipStream_t stream) {
    const int*   prev_kc   = (const int*)d_in[0];
    const int*   curr_kc   = (const int*)d_in[1];
    const int*   prev_corr = (const int*)d_in[2];
    const float* logits    = (const float*)d_in[3];

    float* out     = (float*)d_out;
    float* probs   = out;                 // B*T floats
    float* state_f = out + BB * TT;       // B*N_KCS floats

    bkt_fused_kernel<<<BB, 256, 0, stream>>>(prev_kc, curr_kc, prev_corr,
                                             logits, probs, state_f);
}